// Round 3
// baseline (194.516 us; speedup 1.0000x reference)
//
#include <hip/hip_runtime.h>
#include <hip/hip_bf16.h>

typedef __bf16 bf16;
typedef __attribute__((ext_vector_type(4)))  __bf16 bf16x4;
typedef __attribute__((ext_vector_type(8)))  __bf16 bf16x8;
typedef __attribute__((ext_vector_type(4)))  float  f32x4;
typedef __attribute__((ext_vector_type(16))) float  f32x16;

#define NN   4096
#define INF  256
#define HH   8
#define FF   64
#define HF   512
#define ALPHA_ 0.2f

// ---------------------------------------------------------------------------
// Kernel 1: WhT[n][m] = (h @ W)^T, bf16 out, f32 in.  M=4096, K=256, N=512.
// Tile 64x64, 4 waves, wave = 16 rows. 16x16x32 bf16 MFMA.
// ---------------------------------------------------------------------------
__global__ __launch_bounds__(256) void k_wht(const float* __restrict__ A,
                                             const float* __restrict__ W,
                                             bf16* __restrict__ WhT)
{
    __shared__ bf16 Bs[64][36];          // [n][k], padded
    const int bid = blockIdx.x;
    const int mt = (bid >> 3) << 6;
    const int nt = (bid & 7) << 6;
    const int tid = threadIdx.x;
    const int wv  = tid >> 6;
    const int l   = tid & 63;
    const int l15 = l & 15;
    const int lq  = l >> 4;              // 0..3

    f32x4 acc[4];
#pragma unroll
    for (int nb = 0; nb < 4; ++nb) acc[nb] = (f32x4)0.0f;

    const int krow = tid >> 3;           // 0..31
    const int ncol = (tid & 7) << 3;     // 0,8,...,56

    for (int kb = 0; kb < INF; kb += 32) {
        const float4 w0 = *(const float4*)&W[(kb + krow) * HF + nt + ncol];
        const float4 w1 = *(const float4*)&W[(kb + krow) * HF + nt + ncol + 4];
        __syncthreads();
        Bs[ncol + 0][krow] = (bf16)w0.x; Bs[ncol + 1][krow] = (bf16)w0.y;
        Bs[ncol + 2][krow] = (bf16)w0.z; Bs[ncol + 3][krow] = (bf16)w0.w;
        Bs[ncol + 4][krow] = (bf16)w1.x; Bs[ncol + 5][krow] = (bf16)w1.y;
        Bs[ncol + 6][krow] = (bf16)w1.z; Bs[ncol + 7][krow] = (bf16)w1.w;
        __syncthreads();

        const float* pA = A + (mt + wv * 16 + l15) * INF + kb + (lq << 2);
        const float4 a0 = *(const float4*)pA;
        const float4 a1 = *(const float4*)(pA + 16);
        bf16x8 af;
        af[0] = (bf16)a0.x; af[1] = (bf16)a0.y; af[2] = (bf16)a0.z; af[3] = (bf16)a0.w;
        af[4] = (bf16)a1.x; af[5] = (bf16)a1.y; af[6] = (bf16)a1.z; af[7] = (bf16)a1.w;

#pragma unroll
        for (int nb = 0; nb < 4; ++nb) {
            const bf16* pB = &Bs[(nb << 4) + l15][lq << 2];
            bf16x4 blo = *(const bf16x4*)pB;
            bf16x4 bhi = *(const bf16x4*)(pB + 16);
            bf16x8 bf = __builtin_shufflevector(blo, bhi, 0,1,2,3,4,5,6,7);
            acc[nb] = __builtin_amdgcn_mfma_f32_16x16x32_bf16(af, bf, acc[nb], 0, 0, 0);
        }
    }

    const int m0 = mt + wv * 16 + (lq << 2);
#pragma unroll
    for (int nb = 0; nb < 4; ++nb) {
        const int col = nt + (nb << 4) + l15;
        bf16x4 o;
#pragma unroll
        for (int r = 0; r < 4; ++r) o[r] = (bf16)acc[nb][r];
        *(bf16x4*)&WhT[(size_t)col * NN + m0] = o;
    }
}

// ---------------------------------------------------------------------------
// Kernel 2: per (i,h): t1 = Wh[i,h,:].a1, t2 = Wh[i,h,:].a2;
//           E1=exp(t1), F1=exp(0.2 t1), E2=exp(t2), F2=exp(0.2 t2).  [h][i] f32.
// ---------------------------------------------------------------------------
__global__ __launch_bounds__(256) void k_scores(const bf16* __restrict__ WhT,
                                                const float* __restrict__ a,
                                                float* __restrict__ E1, float* __restrict__ F1,
                                                float* __restrict__ E2, float* __restrict__ F2)
{
    const int h = blockIdx.x >> 4;
    const int i = ((blockIdx.x & 15) << 8) + threadIdx.x;
    float t1 = 0.f, t2 = 0.f;
#pragma unroll 16
    for (int f = 0; f < FF; ++f) {
        float w = (float)WhT[(size_t)(h * FF + f) * NN + i];
        t1 += w * a[h * 128 + f];
        t2 += w * a[h * 128 + 64 + f];
    }
    E1[h * NN + i] = __expf(t1);
    F1[h * NN + i] = __expf(ALPHA_ * t1);
    E2[h * NN + i] = __expf(t2);
    F2[h * NN + i] = __expf(ALPHA_ * t2);
}

// ---------------------------------------------------------------------------
// Kernel 3: fused mask + softmax-weight + aggregation.
// Grid 512 = 128 i-blocks (32 rows) x 4 head-pairs, XCD-clustered.
// 4 waves split j (1024 each). Per j-step of 16: build P fragment in regs,
// 4x mfma_f32_32x32x16_bf16 (2 heads x 2 col-blocks). LDS reduce at end.
// w = adj * max(E1*E2, F1*F2);  out = (P @ Wh) / rowsum(P) + bias.
// ---------------------------------------------------------------------------
__global__ __launch_bounds__(256, 2) void k_gat(const int*  __restrict__ adj,
                                                const bf16* __restrict__ WhT,
                                                const float* __restrict__ E1, const float* __restrict__ F1,
                                                const float* __restrict__ E2, const float* __restrict__ F2,
                                                const float* __restrict__ bias,
                                                float* __restrict__ out)
{
    __shared__ float red[4][128][32];    // [wave][col][i_loc]  64 KB
    __shared__ float dred[4][2][32];     // [wave][hh][i_loc]

    const int bid = blockIdx.x;
    const int x  = bid & 7;
    const int hp = x >> 1;                          // head pair 0..3
    const int ib = ((bid >> 3) << 1) | (x & 1);     // i-block 0..127

    const int tid = threadIdx.x;
    const int wv  = tid >> 6;
    const int l   = tid & 63;
    const int l31 = l & 31;
    const int lh  = l >> 5;

    const int i  = (ib << 5) + l31;
    const int h0 = hp << 1;

    const float e1_0 = E1[h0 * NN + i], e1_1 = E1[(h0 + 1) * NN + i];
    const float f1_0 = F1[h0 * NN + i], f1_1 = F1[(h0 + 1) * NN + i];

    f32x16 acc00 = (f32x16)0.f, acc01 = (f32x16)0.f;
    f32x16 acc10 = (f32x16)0.f, acc11 = (f32x16)0.f;
    float den0 = 0.f, den1 = 0.f;

    const int* adjrow = adj + (size_t)i * NN;
    const float* e2r0 = E2 + h0 * NN;
    const float* e2r1 = e2r0 + NN;
    const float* f2r0 = F2 + h0 * NN;
    const float* f2r1 = f2r0 + NN;
    const bf16* wrow00 = WhT + (size_t)(h0 * FF + l31) * NN;
    const bf16* wrow01 = wrow00 + (size_t)32 * NN;
    const bf16* wrow10 = WhT + (size_t)((h0 + 1) * FF + l31) * NN;
    const bf16* wrow11 = wrow10 + (size_t)32 * NN;

    const int jwbase = (wv << 10) + (lh << 2);

    for (int s = 0; s < 64; ++s) {
        const int j0 = jwbase + (s << 4);
        const int4 av0 = *(const int4*)(adjrow + j0);
        const int4 av1 = *(const int4*)(adjrow + j0 + 8);

        const float4 e2a0 = *(const float4*)(e2r0 + j0);
        const float4 e2b0 = *(const float4*)(e2r0 + j0 + 8);
        const float4 f2a0 = *(const float4*)(f2r0 + j0);
        const float4 f2b0 = *(const float4*)(f2r0 + j0 + 8);
        const float4 e2a1 = *(const float4*)(e2r1 + j0);
        const float4 e2b1 = *(const float4*)(e2r1 + j0 + 8);
        const float4 f2a1 = *(const float4*)(f2r1 + j0);
        const float4 f2b1 = *(const float4*)(f2r1 + j0 + 8);

        bf16x4 b00lo = *(const bf16x4*)(wrow00 + j0), b00hi = *(const bf16x4*)(wrow00 + j0 + 8);
        bf16x4 b01lo = *(const bf16x4*)(wrow01 + j0), b01hi = *(const bf16x4*)(wrow01 + j0 + 8);
        bf16x4 b10lo = *(const bf16x4*)(wrow10 + j0), b10hi = *(const bf16x4*)(wrow10 + j0 + 8);
        bf16x4 b11lo = *(const bf16x4*)(wrow11 + j0), b11hi = *(const bf16x4*)(wrow11 + j0 + 8);

        const float af0 = (float)av0.x, af1 = (float)av0.y, af2 = (float)av0.z, af3 = (float)av0.w;
        const float af4 = (float)av1.x, af5 = (float)av1.y, af6 = (float)av1.z, af7 = (float)av1.w;

        bf16x8 pa0, pa1;
        float w;
        w = fmaxf(e1_0 * e2a0.x, f1_0 * f2a0.x) * af0; den0 += w; pa0[0] = (bf16)w;
        w = fmaxf(e1_0 * e2a0.y, f1_0 * f2a0.y) * af1; den0 += w; pa0[1] = (bf16)w;
        w = fmaxf(e1_0 * e2a0.z, f1_0 * f2a0.z) * af2; den0 += w; pa0[2] = (bf16)w;
        w = fmaxf(e1_0 * e2a0.w, f1_0 * f2a0.w) * af3; den0 += w; pa0[3] = (bf16)w;
        w = fmaxf(e1_0 * e2b0.x, f1_0 * f2b0.x) * af4; den0 += w; pa0[4] = (bf16)w;
        w = fmaxf(e1_0 * e2b0.y, f1_0 * f2b0.y) * af5; den0 += w; pa0[5] = (bf16)w;
        w = fmaxf(e1_0 * e2b0.z, f1_0 * f2b0.z) * af6; den0 += w; pa0[6] = (bf16)w;
        w = fmaxf(e1_0 * e2b0.w, f1_0 * f2b0.w) * af7; den0 += w; pa0[7] = (bf16)w;

        w = fmaxf(e1_1 * e2a1.x, f1_1 * f2a1.x) * af0; den1 += w; pa1[0] = (bf16)w;
        w = fmaxf(e1_1 * e2a1.y, f1_1 * f2a1.y) * af1; den1 += w; pa1[1] = (bf16)w;
        w = fmaxf(e1_1 * e2a1.z, f1_1 * f2a1.z) * af2; den1 += w; pa1[2] = (bf16)w;
        w = fmaxf(e1_1 * e2a1.w, f1_1 * f2a1.w) * af3; den1 += w; pa1[3] = (bf16)w;
        w = fmaxf(e1_1 * e2b1.x, f1_1 * f2b1.x) * af4; den1 += w; pa1[4] = (bf16)w;
        w = fmaxf(e1_1 * e2b1.y, f1_1 * f2b1.y) * af5; den1 += w; pa1[5] = (bf16)w;
        w = fmaxf(e1_1 * e2b1.z, f1_1 * f2b1.z) * af6; den1 += w; pa1[6] = (bf16)w;
        w = fmaxf(e1_1 * e2b1.w, f1_1 * f2b1.w) * af7; den1 += w; pa1[7] = (bf16)w;

        bf16x8 b00 = __builtin_shufflevector(b00lo, b00hi, 0,1,2,3,4,5,6,7);
        bf16x8 b01 = __builtin_shufflevector(b01lo, b01hi, 0,1,2,3,4,5,6,7);
        bf16x8 b10 = __builtin_shufflevector(b10lo, b10hi, 0,1,2,3,4,5,6,7);
        bf16x8 b11 = __builtin_shufflevector(b11lo, b11hi, 0,1,2,3,4,5,6,7);

        acc00 = __builtin_amdgcn_mfma_f32_32x32x16_bf16(pa0, b00, acc00, 0, 0, 0);
        acc01 = __builtin_amdgcn_mfma_f32_32x32x16_bf16(pa0, b01, acc01, 0, 0, 0);
        acc10 = __builtin_amdgcn_mfma_f32_32x32x16_bf16(pa1, b10, acc10, 0, 0, 0);
        acc11 = __builtin_amdgcn_mfma_f32_32x32x16_bf16(pa1, b11, acc11, 0, 0, 0);
    }

    // ---- cross-wave reduction -------------------------------------------
    // C/D layout: col = l&31, row = (r&3) + 8*(r>>2) + 4*(l>>5)
#pragma unroll
    for (int g = 0; g < 4; ++g) {
        const int ir = (g << 3) + (lh << 2);
        f32x4 v0 = { acc00[4*g], acc00[4*g+1], acc00[4*g+2], acc00[4*g+3] };
        f32x4 v1 = { acc01[4*g], acc01[4*g+1], acc01[4*g+2], acc01[4*g+3] };
        f32x4 v2 = { acc10[4*g], acc10[4*g+1], acc10[4*g+2], acc10[4*g+3] };
        f32x4 v3 = { acc11[4*g], acc11[4*g+1], acc11[4*g+2], acc11[4*g+3] };
        *(f32x4*)&red[wv][l31     ][ir] = v0;
        *(f32x4*)&red[wv][32 + l31][ir] = v1;
        *(f32x4*)&red[wv][64 + l31][ir] = v2;
        *(f32x4*)&red[wv][96 + l31][ir] = v3;
    }
    den0 += __shfl_xor(den0, 32, 64);
    den1 += __shfl_xor(den1, 32, 64);
    if (l < 32) { dred[wv][0][l31] = den0; dred[wv][1][l31] = den1; }
    __syncthreads();

    // ---- normalize + bias + store ---------------------------------------
    const int iloc = tid >> 3;           // 0..31
    const int c0   = (tid & 7) << 4;     // 0..112
    const int hh   = c0 >> 6;            // head within pair
    const int irow = (ib << 5) + iloc;
    const float dsum = dred[0][hh][iloc] + dred[1][hh][iloc] +
                       dred[2][hh][iloc] + dred[3][hh][iloc];
    const float rd = 1.0f / dsum;
    float* op = out + (size_t)irow * HF + (hp << 7) + c0;
#pragma unroll
    for (int q = 0; q < 4; ++q) {
        f32x4 o;
#pragma unroll
        for (int r = 0; r < 4; ++r) {
            const int e = (q << 2) + r;
            float sv = red[0][c0+e][iloc] + red[1][c0+e][iloc] +
                       red[2][c0+e][iloc] + red[3][c0+e][iloc];
            o[r] = sv * rd + bias[(hp << 7) + c0 + e];
        }
        *(f32x4*)(op + (q << 2)) = o;
    }
}

// ---------------------------------------------------------------------------
extern "C" void kernel_launch(void* const* d_in, const int* in_sizes, int n_in,
                              void* d_out, int out_size, void* d_ws, size_t ws_size,
                              hipStream_t stream) {
    const float* h    = (const float*)d_in[0];
    const int*   adj  = (const int*)d_in[1];
    const float* W    = (const float*)d_in[2];
    const float* a    = (const float*)d_in[3];
    const float* bias = (const float*)d_in[4];
    float* out = (float*)d_out;

    char* ws = (char*)d_ws;
    bf16*  WhT = (bf16*)ws;                                  // 4 MB
    float* E1  = (float*)(ws + (size_t)(4 << 20));
    float* F1  = E1 + HH * NN;
    float* E2  = F1 + HH * NN;
    float* F2  = E2 + HH * NN;

    hipLaunchKernelGGL(k_wht,    dim3(512), dim3(256), 0, stream, h, W, WhT);
    hipLaunchKernelGGL(k_scores, dim3(128), dim3(256), 0, stream, WhT, a, E1, F1, E2, F2);
    hipLaunchKernelGGL(k_gat,    dim3(512), dim3(256), 0, stream, adj, WhT, E1, F1, E2, F2, bias, out);
}

// Round 6
// 179.401 us; speedup vs baseline: 1.0843x; 1.0843x over previous
//
#include <hip/hip_runtime.h>
#include <hip/hip_bf16.h>

typedef __bf16 bf16;
typedef __attribute__((ext_vector_type(4)))  __bf16 bf16x4;
typedef __attribute__((ext_vector_type(8)))  __bf16 bf16x8;
typedef __attribute__((ext_vector_type(4)))  float  f32x4;
typedef __attribute__((ext_vector_type(16))) float  f32x16;

#define NN   4096
#define INF  256
#define HH   8
#define FF   64
#define HF   512
#define ALPHA_ 0.2f
#define NW   128            // bitmask words per row (4096/32)

// ---------------------------------------------------------------------------
// Kernel 0: pack adj (int32 0/1) -> bitmask, 64 MB -> 2 MB. Pure BW.
// ---------------------------------------------------------------------------
__global__ __launch_bounds__(256) void k_pack(const int* __restrict__ adj,
                                              unsigned* __restrict__ bits)
{
    const int t   = blockIdx.x * 256 + threadIdx.x;       // 0 .. 524287
    const int row = t >> 7;
    const int jw  = t & 127;
    const int* p  = adj + (size_t)row * NN + (jw << 5);
    unsigned m = 0u;
#pragma unroll
    for (int k = 0; k < 8; ++k) {
        const int4 v = *(const int4*)(p + (k << 2));
        m |= (v.x != 0 ? 1u : 0u) << (4 * k);
        m |= (v.y != 0 ? 1u : 0u) << (4 * k + 1);
        m |= (v.z != 0 ? 1u : 0u) << (4 * k + 2);
        m |= (v.w != 0 ? 1u : 0u) << (4 * k + 3);
    }
    bits[t] = m;
}

// ---------------------------------------------------------------------------
// Kernel 1: WhT[n][m] = (h @ W)^T, bf16 out, f32 in.  (unchanged, verified)
// ---------------------------------------------------------------------------
__global__ __launch_bounds__(256) void k_wht(const float* __restrict__ A,
                                             const float* __restrict__ W,
                                             bf16* __restrict__ WhT)
{
    __shared__ bf16 Bs[64][36];
    const int bid = blockIdx.x;
    const int mt = (bid >> 3) << 6;
    const int nt = (bid & 7) << 6;
    const int tid = threadIdx.x;
    const int wv  = tid >> 6;
    const int l   = tid & 63;
    const int l15 = l & 15;
    const int lq  = l >> 4;

    f32x4 acc[4];
#pragma unroll
    for (int nb = 0; nb < 4; ++nb) acc[nb] = (f32x4)0.0f;

    const int krow = tid >> 3;
    const int ncol = (tid & 7) << 3;

    for (int kb = 0; kb < INF; kb += 32) {
        const float4 w0 = *(const float4*)&W[(kb + krow) * HF + nt + ncol];
        const float4 w1 = *(const float4*)&W[(kb + krow) * HF + nt + ncol + 4];
        __syncthreads();
        Bs[ncol + 0][krow] = (bf16)w0.x; Bs[ncol + 1][krow] = (bf16)w0.y;
        Bs[ncol + 2][krow] = (bf16)w0.z; Bs[ncol + 3][krow] = (bf16)w0.w;
        Bs[ncol + 4][krow] = (bf16)w1.x; Bs[ncol + 5][krow] = (bf16)w1.y;
        Bs[ncol + 6][krow] = (bf16)w1.z; Bs[ncol + 7][krow] = (bf16)w1.w;
        __syncthreads();

        const float* pA = A + (mt + wv * 16 + l15) * INF + kb + (lq << 2);
        const float4 a0 = *(const float4*)pA;
        const float4 a1 = *(const float4*)(pA + 16);
        bf16x8 af;
        af[0] = (bf16)a0.x; af[1] = (bf16)a0.y; af[2] = (bf16)a0.z; af[3] = (bf16)a0.w;
        af[4] = (bf16)a1.x; af[5] = (bf16)a1.y; af[6] = (bf16)a1.z; af[7] = (bf16)a1.w;

#pragma unroll
        for (int nb = 0; nb < 4; ++nb) {
            const bf16* pB = &Bs[(nb << 4) + l15][lq << 2];
            bf16x4 blo = *(const bf16x4*)pB;
            bf16x4 bhi = *(const bf16x4*)(pB + 16);
            bf16x8 bf = __builtin_shufflevector(blo, bhi, 0,1,2,3,4,5,6,7);
            acc[nb] = __builtin_amdgcn_mfma_f32_16x16x32_bf16(af, bf, acc[nb], 0, 0, 0);
        }
    }

    const int m0 = mt + wv * 16 + (lq << 2);
#pragma unroll
    for (int nb = 0; nb < 4; ++nb) {
        const int col = nt + (nb << 4) + l15;
        bf16x4 o;
#pragma unroll
        for (int r = 0; r < 4; ++r) o[r] = (bf16)acc[nb][r];
        *(bf16x4*)&WhT[(size_t)col * NN + m0] = o;
    }
}

// ---------------------------------------------------------------------------
// Kernel 2: score factor tables (unchanged, verified)
// ---------------------------------------------------------------------------
__global__ __launch_bounds__(256) void k_scores(const bf16* __restrict__ WhT,
                                                const float* __restrict__ a,
                                                float* __restrict__ E1, float* __restrict__ F1,
                                                float* __restrict__ E2, float* __restrict__ F2)
{
    const int h = blockIdx.x >> 4;
    const int i = ((blockIdx.x & 15) << 8) + threadIdx.x;
    float t1 = 0.f, t2 = 0.f;
#pragma unroll 16
    for (int f = 0; f < FF; ++f) {
        float w = (float)WhT[(size_t)(h * FF + f) * NN + i];
        t1 += w * a[h * 128 + f];
        t2 += w * a[h * 128 + 64 + f];
    }
    E1[h * NN + i] = __expf(t1);
    F1[h * NN + i] = __expf(ALPHA_ * t1);
    E2[h * NN + i] = __expf(t2);
    F2[h * NN + i] = __expf(ALPHA_ * t2);
}

// ---------------------------------------------------------------------------
// Kernel 3 v2: fused mask + softmax-weight + aggregation.
// 512 blocks x 512 threads (8 waves). Block = 32 i-rows x 1 head-pair.
// 8 waves split j (512 each, 32 steps of 16). Contiguous k-slot mapping:
// lane (l31=i, lh) covers j0..j0+7 with j0 = wv*512 + s*16 + lh*8.
// adj via 2MB bitmask (L2-resident). LDS tree-reduce 8->4->1, [row][col]
// layout, conflict-free scalar stores. 66KB LDS -> 2 blk/CU = 16 waves/CU.
// ---------------------------------------------------------------------------
__global__ __launch_bounds__(512, 4) void k_gat(const unsigned* __restrict__ bits,
                                                const bf16* __restrict__ WhT,
                                                const float* __restrict__ E1, const float* __restrict__ F1,
                                                const float* __restrict__ E2, const float* __restrict__ F2,
                                                const float* __restrict__ bias,
                                                float* __restrict__ out)
{
    __shared__ float red[4][32][128];    // [buf][i_loc][col] 64 KB
    __shared__ float dred[8][2][32];     // [wave][hh][i_loc] 2 KB

    const int bid = blockIdx.x;
    const int x  = bid & 7;
    const int hp = x >> 1;                          // head pair 0..3
    const int ib = ((bid >> 3) << 1) | (x & 1);     // i-block 0..127

    const int tid = threadIdx.x;
    const int wv  = tid >> 6;            // 0..7
    const int l   = tid & 63;
    const int l31 = l & 31;
    const int lh  = l >> 5;

    const int i  = (ib << 5) + l31;
    const int h0 = hp << 1;

    const float e1_0 = E1[h0 * NN + i], e1_1 = E1[(h0 + 1) * NN + i];
    const float f1_0 = F1[h0 * NN + i], f1_1 = F1[(h0 + 1) * NN + i];

    f32x16 acc00 = (f32x16)0.f, acc01 = (f32x16)0.f;
    f32x16 acc10 = (f32x16)0.f, acc11 = (f32x16)0.f;
    float den0 = 0.f, den1 = 0.f;

    const unsigned* bitrow = bits + (size_t)i * NW + (wv << 4);   // 16 words = 512 j
    const float* e2r0 = E2 + h0 * NN;
    const float* e2r1 = e2r0 + NN;
    const float* f2r0 = F2 + h0 * NN;
    const float* f2r1 = f2r0 + NN;
    const bf16* wr00 = WhT + (size_t)(h0 * FF + l31) * NN;
    const bf16* wr01 = wr00 + (size_t)32 * NN;
    const bf16* wr10 = WhT + (size_t)((h0 + 1) * FF + l31) * NN;
    const bf16* wr11 = wr10 + (size_t)32 * NN;

    const int jwb = (wv << 9) + (lh << 3);   // wave j-base + lane half

    auto step = [&](int j0, unsigned bsel) {
        const float4 ea0 = *(const float4*)(e2r0 + j0);
        const float4 eb0 = *(const float4*)(e2r0 + j0 + 4);
        const float4 fa0 = *(const float4*)(f2r0 + j0);
        const float4 fb0 = *(const float4*)(f2r0 + j0 + 4);
        bf16x8 pa0, pa1;
        float w;
        w = (bsel & 1u)   ? fmaxf(e1_0 * ea0.x, f1_0 * fa0.x) : 0.f; den0 += w; pa0[0] = (bf16)w;
        w = (bsel & 2u)   ? fmaxf(e1_0 * ea0.y, f1_0 * fa0.y) : 0.f; den0 += w; pa0[1] = (bf16)w;
        w = (bsel & 4u)   ? fmaxf(e1_0 * ea0.z, f1_0 * fa0.z) : 0.f; den0 += w; pa0[2] = (bf16)w;
        w = (bsel & 8u)   ? fmaxf(e1_0 * ea0.w, f1_0 * fa0.w) : 0.f; den0 += w; pa0[3] = (bf16)w;
        w = (bsel & 16u)  ? fmaxf(e1_0 * eb0.x, f1_0 * fb0.x) : 0.f; den0 += w; pa0[4] = (bf16)w;
        w = (bsel & 32u)  ? fmaxf(e1_0 * eb0.y, f1_0 * fb0.y) : 0.f; den0 += w; pa0[5] = (bf16)w;
        w = (bsel & 64u)  ? fmaxf(e1_0 * eb0.z, f1_0 * fb0.z) : 0.f; den0 += w; pa0[6] = (bf16)w;
        w = (bsel & 128u) ? fmaxf(e1_0 * eb0.w, f1_0 * fb0.w) : 0.f; den0 += w; pa0[7] = (bf16)w;

        const float4 ea1 = *(const float4*)(e2r1 + j0);
        const float4 eb1 = *(const float4*)(e2r1 + j0 + 4);
        const float4 fa1 = *(const float4*)(f2r1 + j0);
        const float4 fb1 = *(const float4*)(f2r1 + j0 + 4);
        w = (bsel & 1u)   ? fmaxf(e1_1 * ea1.x, f1_1 * fa1.x) : 0.f; den1 += w; pa1[0] = (bf16)w;
        w = (bsel & 2u)   ? fmaxf(e1_1 * ea1.y, f1_1 * fa1.y) : 0.f; den1 += w; pa1[1] = (bf16)w;
        w = (bsel & 4u)   ? fmaxf(e1_1 * ea1.z, f1_1 * fa1.z) : 0.f; den1 += w; pa1[2] = (bf16)w;
        w = (bsel & 8u)   ? fmaxf(e1_1 * ea1.w, f1_1 * fa1.w) : 0.f; den1 += w; pa1[3] = (bf16)w;
        w = (bsel & 16u)  ? fmaxf(e1_1 * eb1.x, f1_1 * fb1.x) : 0.f; den1 += w; pa1[4] = (bf16)w;
        w = (bsel & 32u)  ? fmaxf(e1_1 * eb1.y, f1_1 * fb1.y) : 0.f; den1 += w; pa1[5] = (bf16)w;
        w = (bsel & 64u)  ? fmaxf(e1_1 * eb1.z, f1_1 * fb1.z) : 0.f; den1 += w; pa1[6] = (bf16)w;
        w = (bsel & 128u) ? fmaxf(e1_1 * eb1.w, f1_1 * fb1.w) : 0.f; den1 += w; pa1[7] = (bf16)w;

        const bf16x8 b00 = *(const bf16x8*)(wr00 + j0);
        const bf16x8 b01 = *(const bf16x8*)(wr01 + j0);
        const bf16x8 b10 = *(const bf16x8*)(wr10 + j0);
        const bf16x8 b11 = *(const bf16x8*)(wr11 + j0);

        acc00 = __builtin_amdgcn_mfma_f32_32x32x16_bf16(pa0, b00, acc00, 0, 0, 0);
        acc01 = __builtin_amdgcn_mfma_f32_32x32x16_bf16(pa0, b01, acc01, 0, 0, 0);
        acc10 = __builtin_amdgcn_mfma_f32_32x32x16_bf16(pa1, b10, acc10, 0, 0, 0);
        acc11 = __builtin_amdgcn_mfma_f32_32x32x16_bf16(pa1, b11, acc11, 0, 0, 0);
    };

    for (int s2 = 0; s2 < 16; ++s2) {
        const unsigned adjw = bitrow[s2];
        const int jb = jwb + (s2 << 5);
        step(jb,      (adjw >> (lh << 3)) & 0xffu);
        step(jb + 16, (adjw >> (16 + (lh << 3))) & 0xffu);
    }

    // ---- reduction: den ---------------------------------------------------
    den0 += __shfl_xor(den0, 32, 64);
    den1 += __shfl_xor(den1, 32, 64);
    if (l < 32) { dred[wv][0][l31] = den0; dred[wv][1][l31] = den1; }

    // ---- reduction: acc, 2-stage tree (waves 0-3 store, 4-7 add) ---------
    // C/D layout: col = l&31 (feature), row = (r&3) + 8*(r>>2) + 4*lh (i_loc)
    if (wv < 4) {
        float* rb = &red[wv][0][0];
#pragma unroll
        for (int g = 0; g < 4; ++g) {
            const int ir = (g << 3) + (lh << 2);
#pragma unroll
            for (int r = 0; r < 4; ++r) {
                rb[(ir + r) * 128 + l31     ] = acc00[4*g + r];
                rb[(ir + r) * 128 + 32 + l31] = acc01[4*g + r];
                rb[(ir + r) * 128 + 64 + l31] = acc10[4*g + r];
                rb[(ir + r) * 128 + 96 + l31] = acc11[4*g + r];
            }
        }
    }
    __syncthreads();
    if (wv >= 4) {
        float* rb = &red[wv - 4][0][0];
#pragma unroll
        for (int g = 0; g < 4; ++g) {
            const int ir = (g << 3) + (lh << 2);
#pragma unroll
            for (int r = 0; r < 4; ++r) {
                rb[(ir + r) * 128 + l31     ] += acc00[4*g + r];
                rb[(ir + r) * 128 + 32 + l31] += acc01[4*g + r];
                rb[(ir + r) * 128 + 64 + l31] += acc10[4*g + r];
                rb[(ir + r) * 128 + 96 + l31] += acc11[4*g + r];
            }
        }
    }
    __syncthreads();

    // ---- normalize + bias + store ----------------------------------------
    const int iloc = tid >> 4;           // 0..31
    const int c0   = (tid & 15) << 3;    // 0..120, 8 cols per thread
    const int hh   = c0 >> 6;            // head within pair
    const float dsum = dred[0][hh][iloc] + dred[1][hh][iloc] + dred[2][hh][iloc] + dred[3][hh][iloc]
                     + dred[4][hh][iloc] + dred[5][hh][iloc] + dred[6][hh][iloc] + dred[7][hh][iloc];
    const float rd = 1.0f / dsum;
    float* op = out + (size_t)((ib << 5) + iloc) * HF + (hp << 7) + c0;
    const float* bp = bias + (hp << 7) + c0;
#pragma unroll
    for (int q = 0; q < 2; ++q) {
        f32x4 o;
#pragma unroll
        for (int r = 0; r < 4; ++r) {
            const int e = (q << 2) + r;
            const float sv = red[0][iloc][c0 + e] + red[1][iloc][c0 + e]
                           + red[2][iloc][c0 + e] + red[3][iloc][c0 + e];
            o[r] = sv * rd + bp[e];
        }
        *(f32x4*)(op + (q << 2)) = o;
    }
}

// ---------------------------------------------------------------------------
extern "C" void kernel_launch(void* const* d_in, const int* in_sizes, int n_in,
                              void* d_out, int out_size, void* d_ws, size_t ws_size,
                              hipStream_t stream) {
    const float* h    = (const float*)d_in[0];
    const int*   adj  = (const int*)d_in[1];
    const float* W    = (const float*)d_in[2];
    const float* a    = (const float*)d_in[3];
    const float* bias = (const float*)d_in[4];
    float* out = (float*)d_out;

    char* ws = (char*)d_ws;
    bf16*     WhT  = (bf16*)ws;                                   // 4 MB
    float*    E1   = (float*)(ws + (size_t)(4 << 20));            // 4 x 128 KB
    float*    F1   = E1 + HH * NN;
    float*    E2   = F1 + HH * NN;
    float*    F2   = E2 + HH * NN;
    unsigned* bits = (unsigned*)(ws + (size_t)(4 << 20) + (512 << 10)); // 2 MB

    hipLaunchKernelGGL(k_pack,   dim3(2048), dim3(256), 0, stream, adj, bits);
    hipLaunchKernelGGL(k_wht,    dim3(512),  dim3(256), 0, stream, h, W, WhT);
    hipLaunchKernelGGL(k_scores, dim3(128),  dim3(256), 0, stream, WhT, a, E1, F1, E2, F2);
    hipLaunchKernelGGL(k_gat,    dim3(512),  dim3(512), 0, stream, bits, WhT, E1, F1, E2, F2, bias, out);
}

// Round 10
// 138.026 us; speedup vs baseline: 1.4093x; 1.2998x over previous
//
#include <hip/hip_runtime.h>
#include <hip/hip_bf16.h>

typedef __bf16 bf16;
typedef __attribute__((ext_vector_type(4)))  __bf16 bf16x4;
typedef __attribute__((ext_vector_type(8)))  __bf16 bf16x8;
typedef __attribute__((ext_vector_type(4)))  float  f32x4;
typedef __attribute__((ext_vector_type(16))) float  f32x16;

#define NN   4096
#define INF  256
#define HH   8
#define FF   64
#define HF   512
#define ALPHA_ 0.2f
#define NW   128            // bitmask words per row (4096/32)

// ---------------------------------------------------------------------------
// Kernel 0: pack adj (int32 0/1) -> bitmask, 64 MB -> 2 MB. Pure BW.
// ---------------------------------------------------------------------------
__global__ __launch_bounds__(256) void k_pack(const int* __restrict__ adj,
                                              unsigned* __restrict__ bits)
{
    const int t   = blockIdx.x * 256 + threadIdx.x;       // 0 .. 524287
    const int row = t >> 7;
    const int jw  = t & 127;
    const int* p  = adj + (size_t)row * NN + (jw << 5);
    unsigned m = 0u;
#pragma unroll
    for (int k = 0; k < 8; ++k) {
        const int4 v = *(const int4*)(p + (k << 2));
        m |= (v.x != 0 ? 1u : 0u) << (4 * k);
        m |= (v.y != 0 ? 1u : 0u) << (4 * k + 1);
        m |= (v.z != 0 ? 1u : 0u) << (4 * k + 2);
        m |= (v.w != 0 ? 1u : 0u) << (4 * k + 3);
    }
    bits[t] = m;
}

// ---------------------------------------------------------------------------
// Kernel 1: WhT[n][m] = (h @ W)^T, bf16 out, f32 in.  (unchanged, verified)
// ---------------------------------------------------------------------------
__global__ __launch_bounds__(256) void k_wht(const float* __restrict__ A,
                                             const float* __restrict__ W,
                                             bf16* __restrict__ WhT)
{
    __shared__ bf16 Bs[64][36];
    const int bid = blockIdx.x;
    const int mt = (bid >> 3) << 6;
    const int nt = (bid & 7) << 6;
    const int tid = threadIdx.x;
    const int wv  = tid >> 6;
    const int l   = tid & 63;
    const int l15 = l & 15;
    const int lq  = l >> 4;

    f32x4 acc[4];
#pragma unroll
    for (int nb = 0; nb < 4; ++nb) acc[nb] = (f32x4)0.0f;

    const int krow = tid >> 3;
    const int ncol = (tid & 7) << 3;

    for (int kb = 0; kb < INF; kb += 32) {
        const float4 w0 = *(const float4*)&W[(kb + krow) * HF + nt + ncol];
        const float4 w1 = *(const float4*)&W[(kb + krow) * HF + nt + ncol + 4];
        __syncthreads();
        Bs[ncol + 0][krow] = (bf16)w0.x; Bs[ncol + 1][krow] = (bf16)w0.y;
        Bs[ncol + 2][krow] = (bf16)w0.z; Bs[ncol + 3][krow] = (bf16)w0.w;
        Bs[ncol + 4][krow] = (bf16)w1.x; Bs[ncol + 5][krow] = (bf16)w1.y;
        Bs[ncol + 6][krow] = (bf16)w1.z; Bs[ncol + 7][krow] = (bf16)w1.w;
        __syncthreads();

        const float* pA = A + (mt + wv * 16 + l15) * INF + kb + (lq << 2);
        const float4 a0 = *(const float4*)pA;
        const float4 a1 = *(const float4*)(pA + 16);
        bf16x8 af;
        af[0] = (bf16)a0.x; af[1] = (bf16)a0.y; af[2] = (bf16)a0.z; af[3] = (bf16)a0.w;
        af[4] = (bf16)a1.x; af[5] = (bf16)a1.y; af[6] = (bf16)a1.z; af[7] = (bf16)a1.w;

#pragma unroll
        for (int nb = 0; nb < 4; ++nb) {
            const bf16* pB = &Bs[(nb << 4) + l15][lq << 2];
            bf16x4 blo = *(const bf16x4*)pB;
            bf16x4 bhi = *(const bf16x4*)(pB + 16);
            bf16x8 bf = __builtin_shufflevector(blo, bhi, 0,1,2,3,4,5,6,7);
            acc[nb] = __builtin_amdgcn_mfma_f32_16x16x32_bf16(af, bf, acc[nb], 0, 0, 0);
        }
    }

    const int m0 = mt + wv * 16 + (lq << 2);
#pragma unroll
    for (int nb = 0; nb < 4; ++nb) {
        const int col = nt + (nb << 4) + l15;
        bf16x4 o;
#pragma unroll
        for (int r = 0; r < 4; ++r) o[r] = (bf16)acc[nb][r];
        *(bf16x4*)&WhT[(size_t)col * NN + m0] = o;
    }
}

// ---------------------------------------------------------------------------
// Kernel 2: score factor tables (unchanged, verified)
// ---------------------------------------------------------------------------
__global__ __launch_bounds__(256) void k_scores(const bf16* __restrict__ WhT,
                                                const float* __restrict__ a,
                                                float* __restrict__ E1, float* __restrict__ F1,
                                                float* __restrict__ E2, float* __restrict__ F2)
{
    const int h = blockIdx.x >> 4;
    const int i = ((blockIdx.x & 15) << 8) + threadIdx.x;
    float t1 = 0.f, t2 = 0.f;
#pragma unroll 16
    for (int f = 0; f < FF; ++f) {
        float w = (float)WhT[(size_t)(h * FF + f) * NN + i];
        t1 += w * a[h * 128 + f];
        t2 += w * a[h * 128 + 64 + f];
    }
    E1[h * NN + i] = __expf(t1);
    F1[h * NN + i] = __expf(ALPHA_ * t1);
    E2[h * NN + i] = __expf(t2);
    F2[h * NN + i] = __expf(ALPHA_ * t2);
}

// ---------------------------------------------------------------------------
// Kernel 3 v3: fused mask + softmax-weight + aggregation.
// Grid 1024 = 128 i-blocks x 8 heads; bid&7 = head -> per-XCD L2 slice
// (512KB WhT + 64KB E/F). 512 threads = 8 waves, 8-way j-split (512 j each).
// Per wave: ONE head, 2 MFMA tiles (32 AGPR), 6 loads/step -> per-step
// footprint ~50 VGPR so the compiler can pipeline 2 steps inside the
// 128-reg (512,4) budget. LDS 33KB.
// ---------------------------------------------------------------------------
__global__ __launch_bounds__(512, 4) void k_gat(const unsigned* __restrict__ bits,
                                                const bf16* __restrict__ WhT,
                                                const float* __restrict__ E1, const float* __restrict__ F1,
                                                const float* __restrict__ E2, const float* __restrict__ F2,
                                                const float* __restrict__ bias,
                                                float* __restrict__ out)
{
    __shared__ float red[4][32][64];     // [buf][i_loc][col] 32 KB
    __shared__ float dred[8][32];        // [wave][i_loc] 1 KB

    const int bid = blockIdx.x;
    const int hd = bid & 7;              // head 0..7 (XCD-local slice)
    const int ib = bid >> 3;             // i-block 0..127

    const int tid = threadIdx.x;
    const int wv  = tid >> 6;            // 0..7 = j-split
    const int l   = tid & 63;
    const int l31 = l & 31;
    const int lh  = l >> 5;

    const int i = (ib << 5) + l31;

    const float e1 = E1[hd * NN + i];
    const float f1 = F1[hd * NN + i];

    f32x16 acc0 = (f32x16)0.f, acc1 = (f32x16)0.f;
    float den = 0.f;

    const unsigned* bitrow = bits + (size_t)i * NW + (wv << 4);   // 16 words = 512 j
    const float* e2r = E2 + hd * NN;
    const float* f2r = F2 + hd * NN;
    const bf16* wr0 = WhT + (size_t)(hd * FF + l31) * NN;
    const bf16* wr1 = wr0 + (size_t)32 * NN;

    const int jwb = (wv << 9) + (lh << 3);   // wave j-base + lane half

    auto step = [&](int j0, unsigned bsel) {
        const float4 ea = *(const float4*)(e2r + j0);
        const float4 eb = *(const float4*)(e2r + j0 + 4);
        const float4 fa = *(const float4*)(f2r + j0);
        const float4 fb = *(const float4*)(f2r + j0 + 4);
        bf16x8 pa;
        float w;
        w = (bsel & 1u)   ? fmaxf(e1 * ea.x, f1 * fa.x) : 0.f; den += w; pa[0] = (bf16)w;
        w = (bsel & 2u)   ? fmaxf(e1 * ea.y, f1 * fa.y) : 0.f; den += w; pa[1] = (bf16)w;
        w = (bsel & 4u)   ? fmaxf(e1 * ea.z, f1 * fa.z) : 0.f; den += w; pa[2] = (bf16)w;
        w = (bsel & 8u)   ? fmaxf(e1 * ea.w, f1 * fa.w) : 0.f; den += w; pa[3] = (bf16)w;
        w = (bsel & 16u)  ? fmaxf(e1 * eb.x, f1 * fb.x) : 0.f; den += w; pa[4] = (bf16)w;
        w = (bsel & 32u)  ? fmaxf(e1 * eb.y, f1 * fb.y) : 0.f; den += w; pa[5] = (bf16)w;
        w = (bsel & 64u)  ? fmaxf(e1 * eb.z, f1 * fb.z) : 0.f; den += w; pa[6] = (bf16)w;
        w = (bsel & 128u) ? fmaxf(e1 * eb.w, f1 * fb.w) : 0.f; den += w; pa[7] = (bf16)w;

        const bf16x8 b0 = *(const bf16x8*)(wr0 + j0);
        const bf16x8 b1 = *(const bf16x8*)(wr1 + j0);

        acc0 = __builtin_amdgcn_mfma_f32_32x32x16_bf16(pa, b0, acc0, 0, 0, 0);
        acc1 = __builtin_amdgcn_mfma_f32_32x32x16_bf16(pa, b1, acc1, 0, 0, 0);
    };

    for (int s2 = 0; s2 < 16; ++s2) {
        const unsigned adjw = bitrow[s2];
        const int jb = jwb + (s2 << 5);
        step(jb,      (adjw >> (lh << 3)) & 0xffu);
        step(jb + 16, (adjw >> (16 + (lh << 3))) & 0xffu);
    }

    // ---- reduction: den ---------------------------------------------------
    den += __shfl_xor(den, 32, 64);
    if (l < 32) dred[wv][l31] = den;

    // ---- reduction: acc, 2-stage tree (waves 0-3 store, 4-7 add) ---------
    // C/D layout: col = l&31 (feature), row = (r&3) + 8*(r>>2) + 4*lh (i_loc)
    if (wv < 4) {
        float* rb = &red[wv][0][0];
#pragma unroll
        for (int g = 0; g < 4; ++g) {
            const int ir = (g << 3) + (lh << 2);
#pragma unroll
            for (int r = 0; r < 4; ++r) {
                rb[(ir + r) * 64 + l31     ] = acc0[4*g + r];
                rb[(ir + r) * 64 + 32 + l31] = acc1[4*g + r];
            }
        }
    }
    __syncthreads();
    if (wv >= 4) {
        float* rb = &red[wv - 4][0][0];
#pragma unroll
        for (int g = 0; g < 4; ++g) {
            const int ir = (g << 3) + (lh << 2);
#pragma unroll
            for (int r = 0; r < 4; ++r) {
                rb[(ir + r) * 64 + l31     ] += acc0[4*g + r];
                rb[(ir + r) * 64 + 32 + l31] += acc1[4*g + r];
            }
        }
    }
    __syncthreads();

    // ---- normalize + bias + store ----------------------------------------
    const int iloc = tid >> 4;           // 0..31
    const int c0   = (tid & 15) << 2;    // 0..60, 4 cols per thread
    const float dsum = dred[0][iloc] + dred[1][iloc] + dred[2][iloc] + dred[3][iloc]
                     + dred[4][iloc] + dred[5][iloc] + dred[6][iloc] + dred[7][iloc];
    const float rd = 1.0f / dsum;
    f32x4 o;
#pragma unroll
    for (int r = 0; r < 4; ++r) {
        const float sv = red[0][iloc][c0 + r] + red[1][iloc][c0 + r]
                       + red[2][iloc][c0 + r] + red[3][iloc][c0 + r];
        o[r] = sv * rd + bias[(hd << 6) + c0 + r];
    }
    *(f32x4*)&out[(size_t)((ib << 5) + iloc) * HF + (hd << 6) + c0] = o;
}

// ---------------------------------------------------------------------------
extern "C" void kernel_launch(void* const* d_in, const int* in_sizes, int n_in,
                              void* d_out, int out_size, void* d_ws, size_t ws_size,
                              hipStream_t stream) {
    const float* h    = (const float*)d_in[0];
    const int*   adj  = (const int*)d_in[1];
    const float* W    = (const float*)d_in[2];
    const float* a    = (const float*)d_in[3];
    const float* bias = (const float*)d_in[4];
    float* out = (float*)d_out;

    char* ws = (char*)d_ws;
    bf16*     WhT  = (bf16*)ws;                                   // 4 MB
    float*    E1   = (float*)(ws + (size_t)(4 << 20));            // 4 x 128 KB
    float*    F1   = E1 + HH * NN;
    float*    E2   = F1 + HH * NN;
    float*    F2   = E2 + HH * NN;
    unsigned* bits = (unsigned*)(ws + (size_t)(4 << 20) + (512 << 10)); // 2 MB

    hipLaunchKernelGGL(k_pack,   dim3(2048), dim3(256), 0, stream, adj, bits);
    hipLaunchKernelGGL(k_wht,    dim3(512),  dim3(256), 0, stream, h, W, WhT);
    hipLaunchKernelGGL(k_scores, dim3(128),  dim3(256), 0, stream, WhT, a, E1, F1, E2, F2);
    hipLaunchKernelGGL(k_gat,    dim3(1024), dim3(512), 0, stream, bits, WhT, E1, F1, E2, F2, bias, out);
}